// Round 4
// baseline (207.229 us; speedup 1.0000x reference)
//
#include <hip/hip_runtime.h>
#include <hip/hip_fp16.h>

#define N_NODES 100000
#define E_EDGES 1600000
#define IN_C 128
#define HID_C 64
#define OUT_C 32
#define BNODES 64                                   // nodes per bucket (dst>>6)
#define NBUCK ((N_NODES + BNODES - 1) / BNODES)     // 1563
#define MAXB 2048                                   // bucket cap (mean 1024, sigma~32)
#define NCHUNK 256                                  // edge chunks (privatized sort)
#define CHUNK_E (E_EDGES / NCHUNK)                  // 6250
#define SCAN_N (NBUCK * NCHUNK)                     // 400128 counts
#define SCAN_NB (SCAN_N / 256)                      // 1563 blocks (bsums[i] pairs with hist row i)

// v_fma_mix_f32: acc(f32) += cvt_f32(f16 half of u) * wt(f32). One VALU per channel-value
// (vs cvt+add = 2), fp32 accumulation preserved exactly.
#define FMX_LO(acc, u, wt) asm("v_fma_mix_f32 %0, %1, %2, %0 op_sel:[0,0,0] op_sel_hi:[1,0,0]" \
                               : "+v"(acc) : "v"(u), "v"(wt))
#define FMX_HI(acc, u, wt) asm("v_fma_mix_f32 %0, %1, %2, %0 op_sel:[1,0,0] op_sel_hi:[1,0,0]" \
                               : "+v"(acc) : "v"(u), "v"(wt))

// NOTE: macro param must NOT be named 'w'/'x'/'y'/'z' — it would substitute into the
// vector member access (v).w (round-2 compile failure).
#define ACC8(v, wt) do { \
        FMX_LO(a0, (v).x, wt); FMX_HI(a1, (v).x, wt); \
        FMX_LO(a2, (v).y, wt); FMX_HI(a3, (v).y, wt); \
        FMX_LO(a4, (v).z, wt); FMX_HI(a5, (v).z, wt); \
        FMX_LO(a6, (v).w, wt); FMX_HI(a7, (v).w, wt); } while (0)

// chunk<->block swizzle: consecutive chunks land on the same XCD (blockIdx%8 heuristic),
// so adjacent pairs-windows (shared 64B lines) merge in one L2 instead of ping-ponging.
__device__ __forceinline__ int chunk_of_block(int b) { return (b & 7) * (NCHUNK / 8) + (b >> 3); }

// ---- chunk histogram: block k histograms its 6250-edge slice in LDS (1024 thr) ----
__global__ __launch_bounds__(1024) void chunk_hist_kernel(const int* __restrict__ dst,
                                                          int* __restrict__ hist) {
    __shared__ int h[NBUCK];
    for (int i = threadIdx.x; i < NBUCK; i += 1024) h[i] = 0;
    __syncthreads();
    const int chunk = chunk_of_block(blockIdx.x);
    const int base = chunk * CHUNK_E;
    for (int j = threadIdx.x; j < CHUNK_E; j += 1024)
        atomicAdd(&h[dst[base + j] >> 6], 1);
    __syncthreads();
    for (int i = threadIdx.x; i < NBUCK; i += 1024)
        hist[i * NCHUNK + chunk] = h[i];
}

// ---- scan stage 1: per-256-block exclusive scan; block sums out.
//      Consumers add bsums[] themselves — no scan3 pass. ----
__global__ void scan1_kernel(int* __restrict__ data, int* __restrict__ bsums) {
    __shared__ int s[256];
    int i = blockIdx.x * 256 + threadIdx.x;
    int v = data[i];
    s[threadIdx.x] = v;
    __syncthreads();
    for (int off = 1; off < 256; off <<= 1) {
        int t = (threadIdx.x >= off) ? s[threadIdx.x - off] : 0;
        __syncthreads();
        s[threadIdx.x] += t;
        __syncthreads();
    }
    data[i] = s[threadIdx.x] - v;                   // exclusive within block
    if (threadIdx.x == 255) bsums[blockIdx.x] = s[255];
}

// ---- scan stage 2: exclusive scan of the 1563 block sums (single block, 2 passes) ----
__global__ __launch_bounds__(1024) void scan2_kernel(int* __restrict__ bsums) {
    __shared__ int s[1024];
    int total = 0;
    for (int base = 0; base < SCAN_NB; base += 1024) {
        int i = base + threadIdx.x;
        int v = (i < SCAN_NB) ? bsums[i] : 0;
        s[threadIdx.x] = v;
        __syncthreads();
        for (int off = 1; off < 1024; off <<= 1) {
            int t = (threadIdx.x >= off) ? s[threadIdx.x - off] : 0;
            __syncthreads();
            s[threadIdx.x] += t;
            __syncthreads();
        }
        if (i < SCAN_NB) bsums[i] = total + s[threadIdx.x] - v;
        total += s[1023];
        __syncthreads();
    }
}

// ---- chunk fill: block k scatters its slice into PRIVATE windows.
//      Global offset of (bucket i, chunk) = hist[i*256+chunk] + bsums[i]. ----
__global__ __launch_bounds__(1024) void chunk_fill_kernel(const int* __restrict__ src,
                                                          const int* __restrict__ dst,
                                                          const int* __restrict__ hist,
                                                          const int* __restrict__ bsums,
                                                          unsigned* __restrict__ pairs) {
    __shared__ int cur[NBUCK];
    const int chunk = chunk_of_block(blockIdx.x);
    for (int i = threadIdx.x; i < NBUCK; i += 1024)
        cur[i] = hist[i * NCHUNK + chunk] + bsums[i];
    __syncthreads();
    const int base = chunk * CHUNK_E;
    for (int j = threadIdx.x; j < CHUNK_E; j += 1024) {
        int d = dst[base + j];
        int pos = atomicAdd(&cur[d >> 6], 1);
        pairs[pos] = ((unsigned)src[base + j] << 6) | (unsigned)(d & 63);
    }
}

// ---- per-bucket counting sort -> node-level CSR, in place (LDS stage).
//      Sorted permutation staged in LDS (so[]) and written back COALESCED. ----
__global__ __launch_bounds__(256) void bucket_sort_kernel(const int* __restrict__ hist,
                                                          const int* __restrict__ bsums,
                                                          unsigned* __restrict__ pairs,
                                                          int* __restrict__ row_ptr,
                                                          float* __restrict__ dinv) {
    __shared__ unsigned sp[MAXB];
    __shared__ unsigned so[MAXB];
    __shared__ int hcnt[BNODES], scn[BNODES], cur[BNODES];
    const int b = blockIdx.x;
    const int beg = hist[b * NCHUNK] + bsums[b];
    const int end = (b + 1 < NBUCK) ? hist[(b + 1) * NCHUNK] + bsums[b + 1] : E_EDGES;
    const int cnt = end - beg;
    if (threadIdx.x < BNODES) hcnt[threadIdx.x] = 0;
    __syncthreads();
    for (int j = threadIdx.x; j < cnt; j += 256) {
        unsigned p = pairs[beg + j];
        sp[j] = p;
        atomicAdd(&hcnt[p & 63], 1);
    }
    __syncthreads();
    if (threadIdx.x < BNODES) scn[threadIdx.x] = hcnt[threadIdx.x];
    __syncthreads();
    for (int off = 1; off < BNODES; off <<= 1) {
        int t = 0;
        if (threadIdx.x < BNODES && threadIdx.x >= off) t = scn[threadIdx.x - off];
        __syncthreads();
        if (threadIdx.x < BNODES) scn[threadIdx.x] += t;
        __syncthreads();
    }
    if (threadIdx.x < BNODES) {
        int ex = scn[threadIdx.x] - hcnt[threadIdx.x];   // exclusive
        cur[threadIdx.x] = ex;
        int node = b * BNODES + threadIdx.x;
        if (node < N_NODES) {
            row_ptr[node] = beg + ex;
            dinv[node] = rsqrtf((float)hcnt[threadIdx.x] + 1.0f);
        }
    }
    if (threadIdx.x == 0 && b == NBUCK - 1) row_ptr[N_NODES] = E_EDGES;
    __syncthreads();
    for (int j = threadIdx.x; j < cnt; j += 256) {
        unsigned p = sp[j];
        int pos = atomicAdd(&cur[p & 63], 1);
        so[pos] = p >> 6;                               // scatter stays in LDS
    }
    __syncthreads();
    for (int j = threadIdx.x; j < cnt; j += 256)
        pairs[beg + j] = so[j];                         // coalesced writeback
}

// ---- hs(fp16) = dinv[row] * (x @ W1) : 4 rows x 8 cols per thread, 128 rows/block ----
__global__ __launch_bounds__(256) void gemm1_kernel(const float* __restrict__ x,
                                                    const float* __restrict__ W1,
                                                    const float* __restrict__ dinv,
                                                    __half* __restrict__ hs) {
    __shared__ float sW[IN_C * HID_C];
    for (int i = threadIdx.x; i < IN_C * HID_C; i += 256) sW[i] = W1[i];
    __syncthreads();
    const int cg = (threadIdx.x & 7) * 8;
    const int row0 = blockIdx.x * 128 + (threadIdx.x >> 3) * 4;
    float acc[4][8];
#pragma unroll
    for (int r = 0; r < 4; ++r)
#pragma unroll
        for (int c = 0; c < 8; ++c) acc[r][c] = 0.f;

    int rr[4];
#pragma unroll
    for (int r = 0; r < 4; ++r) rr[r] = min(row0 + r, N_NODES - 1);

    const float4* x4 = (const float4*)x;
#pragma unroll 2
    for (int k4 = 0; k4 < IN_C / 4; ++k4) {
        float4 xv[4];
#pragma unroll
        for (int r = 0; r < 4; ++r) xv[r] = x4[(size_t)rr[r] * (IN_C / 4) + k4];
        float xs[4][4];
#pragma unroll
        for (int r = 0; r < 4; ++r) {
            xs[r][0] = xv[r].x; xs[r][1] = xv[r].y; xs[r][2] = xv[r].z; xs[r][3] = xv[r].w;
        }
#pragma unroll
        for (int kk = 0; kk < 4; ++kk) {
            const float4* wp = (const float4*)(sW + (k4 * 4 + kk) * HID_C + cg);
            float4 w0 = wp[0], w1 = wp[1];
            float wv[8] = {w0.x, w0.y, w0.z, w0.w, w1.x, w1.y, w1.z, w1.w};
#pragma unroll
            for (int r = 0; r < 4; ++r)
#pragma unroll
                for (int c = 0; c < 8; ++c)
                    acc[r][c] = fmaf(xs[r][kk], wv[c], acc[r][c]);
        }
    }
#pragma unroll
    for (int r = 0; r < 4; ++r) {
        int row = row0 + r;
        if (row < N_NODES) {
            float dv = dinv[row];
            union { float4 f; __half2 h[4]; } u;
#pragma unroll
            for (int q = 0; q < 4; ++q)
                u.h[q] = __floats2half2_rn(acc[r][2 * q] * dv, acc[r][2 * q + 1] * dv);
            *(float4*)(hs + (size_t)row * HID_C + cg) = u.f;   // 16 B packed store
        }
    }
}

// ---- layer-1 aggregate FUSED with gemm2. 8 nodes/wave, 8 lanes/node, uint4 (16B =
//      8 fp16 channels) per lane. Main loop now 16 gathers in flight (latency-bound
//      regime, huge VGPR headroom), then 8-wide, then fully-predicated 8-deep tail. ----
__global__ __launch_bounds__(256) void agg1_gemm2_kernel(const int* __restrict__ row_ptr,
                                                         const int* __restrict__ col,
                                                         const __half* __restrict__ hs,
                                                         const float* __restrict__ dinv,
                                                         const float* __restrict__ b1,
                                                         const float* __restrict__ W2,
                                                         __half* __restrict__ gs) {
    __shared__ float sW[HID_C * OUT_C];                 // 8 KB, [k][c] row-major
    __shared__ float sh[32 * 68];                       // 32 nodes x 64ch, stride 68 (bank-spread)
    for (int i = threadIdx.x; i < HID_C * OUT_C; i += 256) sW[i] = W2[i];
    const int ln = threadIdx.x >> 3;                    // node slot 0..31
    const int cl = threadIdx.x & 7;                     // lane in node: channels 8cl..8cl+7
    const int node = blockIdx.x * 32 + ln;              // grid 3125 exact
    const int beg = row_ptr[node], end = row_ptr[node + 1];
    const char* hsb = (const char*)hs;
    const int lo = cl * 16;                             // byte offset within 128-B row
    float one = 1.0f;
    float a0 = 0.f, a1 = 0.f, a2 = 0.f, a3 = 0.f, a4 = 0.f, a5 = 0.f, a6 = 0.f, a7 = 0.f;
    {
        uint4 sv = *(const uint4*)(hsb + node * 128 + lo);   // self loop
        ACC8(sv, one);
    }
    int j = beg;
    for (; j + 16 <= end; j += 16) {                    // 16 independent gathers in flight
        int idx[16];
#pragma unroll
        for (int k = 0; k < 16; ++k) idx[k] = col[j + k];
        uint4 v[16];
#pragma unroll
        for (int k = 0; k < 16; ++k) v[k] = *(const uint4*)(hsb + idx[k] * 128 + lo);
#pragma unroll
        for (int k = 0; k < 16; ++k) ACC8(v[k], one);
    }
    for (; j + 8 <= end; j += 8) {
        int i0 = col[j],     i1 = col[j + 1], i2 = col[j + 2], i3 = col[j + 3];
        int i4 = col[j + 4], i5 = col[j + 5], i6 = col[j + 6], i7 = col[j + 7];
        uint4 v0 = *(const uint4*)(hsb + i0 * 128 + lo);
        uint4 v1 = *(const uint4*)(hsb + i1 * 128 + lo);
        uint4 v2 = *(const uint4*)(hsb + i2 * 128 + lo);
        uint4 v3 = *(const uint4*)(hsb + i3 * 128 + lo);
        uint4 v4 = *(const uint4*)(hsb + i4 * 128 + lo);
        uint4 v5 = *(const uint4*)(hsb + i5 * 128 + lo);
        uint4 v6 = *(const uint4*)(hsb + i6 * 128 + lo);
        uint4 v7 = *(const uint4*)(hsb + i7 * 128 + lo);
        ACC8(v0, one); ACC8(v1, one); ACC8(v2, one); ACC8(v3, one);
        ACC8(v4, one); ACC8(v5, one); ACC8(v6, one); ACC8(v7, one);
    }
    if (j < end) {                                      // predicated tail, 8 deep
        const int e1 = end - 1;
#pragma unroll
        for (int k = 0; k < 8; ++k) {
            int jj = j + k;
            int s = col[min(jj, e1)];
            float wt = (jj < end) ? 1.0f : 0.0f;
            uint4 v = *(const uint4*)(hsb + s * 128 + lo);
            ACC8(v, wt);
        }
    }
    const float dv = dinv[node];
    const float4* b4 = (const float4*)b1;
    float4 bb0 = b4[2 * cl], bb1 = b4[2 * cl + 1];
    float4 h0, h1;
    h0.x = fmaxf(fmaf(dv, a0, bb0.x), 0.f);
    h0.y = fmaxf(fmaf(dv, a1, bb0.y), 0.f);
    h0.z = fmaxf(fmaf(dv, a2, bb0.z), 0.f);
    h0.w = fmaxf(fmaf(dv, a3, bb0.w), 0.f);
    h1.x = fmaxf(fmaf(dv, a4, bb1.x), 0.f);
    h1.y = fmaxf(fmaf(dv, a5, bb1.y), 0.f);
    h1.z = fmaxf(fmaf(dv, a6, bb1.z), 0.f);
    h1.w = fmaxf(fmaf(dv, a7, bb1.w), 0.f);
    *(float4*)&sh[ln * 68 + 8 * cl] = h0;               // h2 row, fp32 in LDS
    *(float4*)&sh[ln * 68 + 8 * cl + 4] = h1;
    __syncthreads();                                    // also covers sW load
    // gs[node][oc..oc+3] = dv * sum_k h2[k] * W2[k][oc..oc+3]
    float g0 = 0.f, g1 = 0.f, g2 = 0.f, g3 = 0.f;
    const int oc = 4 * cl;
#pragma unroll
    for (int k4 = 0; k4 < HID_C / 4; ++k4) {
        float4 hv = *(const float4*)&sh[ln * 68 + 4 * k4];   // bank 4(ln+k4)%32: conflict-free
#pragma unroll
        for (int q = 0; q < 4; ++q) {
            float hq = (q == 0) ? hv.x : (q == 1) ? hv.y : (q == 2) ? hv.z : hv.w;
            float4 wv = *(const float4*)&sW[(4 * k4 + q) * OUT_C + oc];
            g0 = fmaf(hq, wv.x, g0);
            g1 = fmaf(hq, wv.y, g1);
            g2 = fmaf(hq, wv.z, g2);
            g3 = fmaf(hq, wv.w, g3);
        }
    }
    union { uint2 u; __half2 h[2]; } go;
    go.h[0] = __floats2half2_rn(g0 * dv, g1 * dv);
    go.h[1] = __floats2half2_rn(g2 * dv, g3 * dv);
    *(uint2*)(gs + (size_t)node * OUT_C + oc) = go.u;   // 8 B x 8 lanes = 64 B/node
}

// ---- layer-2 aggregate: 16 nodes/wave, 4 lanes/node, uint4 (16B = 8 fp16 ch) per
//      lane. One gather instruction = 16 edges x 64-B rows = 1 KB (2x round-3 width):
//      half the VMEM instrs and addr math per edge. 8 gathers in flight per group. ----
__global__ __launch_bounds__(256) void agg2_kernel(const int* __restrict__ row_ptr,
                                                   const int* __restrict__ col,
                                                   const __half* __restrict__ gsr,
                                                   const float* __restrict__ dinv,
                                                   const float* __restrict__ b2,
                                                   float* __restrict__ out) {
    const int ln = threadIdx.x >> 2;                    // node slot 0..63
    const int cl = threadIdx.x & 3;                     // channels 8cl..8cl+7
    const int node = blockIdx.x * 64 + ln;              // grid 1563 (bounds-checked)
    if (node >= N_NODES) return;
    const int beg = row_ptr[node], end = row_ptr[node + 1];
    const char* gb = (const char*)gsr;
    const int lo = cl * 16;                             // byte offset within 64-B row
    float one = 1.0f;
    float a0 = 0.f, a1 = 0.f, a2 = 0.f, a3 = 0.f, a4 = 0.f, a5 = 0.f, a6 = 0.f, a7 = 0.f;
    {
        uint4 sv = *(const uint4*)(gb + node * 64 + lo);     // self loop
        ACC8(sv, one);
    }
    int j = beg;
    for (; j + 8 <= end; j += 8) {
        int i0 = col[j],     i1 = col[j + 1], i2 = col[j + 2], i3 = col[j + 3];
        int i4 = col[j + 4], i5 = col[j + 5], i6 = col[j + 6], i7 = col[j + 7];
        uint4 v0 = *(const uint4*)(gb + i0 * 64 + lo);
        uint4 v1 = *(const uint4*)(gb + i1 * 64 + lo);
        uint4 v2 = *(const uint4*)(gb + i2 * 64 + lo);
        uint4 v3 = *(const uint4*)(gb + i3 * 64 + lo);
        uint4 v4 = *(const uint4*)(gb + i4 * 64 + lo);
        uint4 v5 = *(const uint4*)(gb + i5 * 64 + lo);
        uint4 v6 = *(const uint4*)(gb + i6 * 64 + lo);
        uint4 v7 = *(const uint4*)(gb + i7 * 64 + lo);
        ACC8(v0, one); ACC8(v1, one); ACC8(v2, one); ACC8(v3, one);
        ACC8(v4, one); ACC8(v5, one); ACC8(v6, one); ACC8(v7, one);
    }
    if (j < end) {                                      // predicated tail, 8 deep
        const int e1 = end - 1;
#pragma unroll
        for (int k = 0; k < 8; ++k) {
            int jj = j + k;
            int s = col[min(jj, e1)];
            float wt = (jj < end) ? 1.0f : 0.0f;
            uint4 v = *(const uint4*)(gb + s * 64 + lo);
            ACC8(v, wt);
        }
    }
    const float dv = dinv[node];
    const float4* b4 = (const float4*)b2;
    float4 bb0 = b4[2 * cl], bb1 = b4[2 * cl + 1];
    float4 o0, o1;
    o0.x = fmaf(dv, a0, bb0.x);
    o0.y = fmaf(dv, a1, bb0.y);
    o0.z = fmaf(dv, a2, bb0.z);
    o0.w = fmaf(dv, a3, bb0.w);
    o1.x = fmaf(dv, a4, bb1.x);
    o1.y = fmaf(dv, a5, bb1.y);
    o1.z = fmaf(dv, a6, bb1.z);
    o1.w = fmaf(dv, a7, bb1.w);
    float* op = out + (size_t)node * OUT_C + 8 * cl;
    *(float4*)op = o0;                                  // 32 B x 4 lanes = 128 B/node
    *(float4*)(op + 4) = o1;
}

extern "C" void kernel_launch(void* const* d_in, const int* in_sizes, int n_in,
                              void* d_out, int out_size, void* d_ws, size_t ws_size,
                              hipStream_t stream) {
    const float* x  = (const float*)d_in[0];   // [N,128]
    const int*   ei = (const int*)d_in[1];     // [2,E]
    const float* W1 = (const float*)d_in[2];   // [128,64]
    const float* b1 = (const float*)d_in[3];   // [64]
    const float* W2 = (const float*)d_in[4];   // [64,32]
    const float* b2 = (const float*)d_in[5];   // [32]
    float* out = (float*)d_out;                // [N,32]

    const int* srcv = ei;
    const int* dstv = ei + E_EDGES;

    // workspace layout (~35 MB)
    float* dinv  = (float*)d_ws;                           // N floats
    __half* hs   = (__half*)(dinv + N_NODES);              // N*64 halves (layer-1 features)
    __half* gs   = hs + (size_t)N_NODES * HID_C;           // N*32 halves (fused agg1+gemm2 out;
                                                           //  must NOT alias hs — read concurrently)
    int* hist      = (int*)(gs + (size_t)N_NODES * HID_C); // NBUCK*NCHUNK (400k)
    int* bsums     = hist + SCAN_N;                        // SCAN_NB (1563)
    int* row_ptr   = bsums + SCAN_NB;                      // N+1
    unsigned* pairs = (unsigned*)(row_ptr + N_NODES + 1);  // E (pairs -> sorted src = col)
    int* col = (int*)pairs;

    // CSR build: chunk-privatized counting sort (scan3 folded into consumers)
    chunk_hist_kernel<<<NCHUNK, 1024, 0, stream>>>(dstv, hist);
    scan1_kernel<<<SCAN_NB, 256, 0, stream>>>(hist, bsums);
    scan2_kernel<<<1, 1024, 0, stream>>>(bsums);
    chunk_fill_kernel<<<NCHUNK, 1024, 0, stream>>>(srcv, dstv, hist, bsums, pairs);
    bucket_sort_kernel<<<NBUCK, 256, 0, stream>>>(hist, bsums, pairs, row_ptr, dinv);

    // layer 1 (+ fused layer-2 GEMM)
    gemm1_kernel<<<(N_NODES + 127) / 128, 256, 0, stream>>>(x, W1, dinv, hs);
    agg1_gemm2_kernel<<<N_NODES / 32, 256, 0, stream>>>(row_ptr, col, hs, dinv, b1, W2, gs);

    // layer 2 aggregate
    agg2_kernel<<<(N_NODES + 63) / 64, 256, 0, stream>>>(row_ptr, col, gs, dinv, b2, out);
}

// Round 5
// 203.690 us; speedup vs baseline: 1.0174x; 1.0174x over previous
//
#include <hip/hip_runtime.h>
#include <hip/hip_fp16.h>

#define N_NODES 100000
#define E_EDGES 1600000
#define IN_C 128
#define HID_C 64
#define OUT_C 32
#define BNODES 256                                  // nodes per bucket (dst>>8)
#define NBUCK ((N_NODES + BNODES - 1) / BNODES)     // 391
#define MAXB 4608                                   // bucket cap (mean 4096, sigma~64)
#define NCHUNK 256                                  // edge chunks (privatized sort)
#define CHUNK_E (E_EDGES / NCHUNK)                  // 6250
#define SCAN_N (NBUCK * NCHUNK)                     // 100096 counts
#define SCAN_NB (SCAN_N / 256)                      // 391 blocks (bsums[i] pairs with hist row i)

// v_fma_mix_f32: acc(f32) += cvt_f32(f16 half of u) * wt(f32). One VALU per channel-value
// (vs cvt+add = 2), fp32 accumulation preserved exactly.
#define FMX_LO(acc, u, wt) asm("v_fma_mix_f32 %0, %1, %2, %0 op_sel:[0,0,0] op_sel_hi:[1,0,0]" \
                               : "+v"(acc) : "v"(u), "v"(wt))
#define FMX_HI(acc, u, wt) asm("v_fma_mix_f32 %0, %1, %2, %0 op_sel:[1,0,0] op_sel_hi:[1,0,0]" \
                               : "+v"(acc) : "v"(u), "v"(wt))

// NOTE: macro param must NOT be named 'w'/'x'/'y'/'z' — it would substitute into the
// vector member access (v).w (round-2 compile failure).
#define ACC8(v, wt) do { \
        FMX_LO(a0, (v).x, wt); FMX_HI(a1, (v).x, wt); \
        FMX_LO(a2, (v).y, wt); FMX_HI(a3, (v).y, wt); \
        FMX_LO(a4, (v).z, wt); FMX_HI(a5, (v).z, wt); \
        FMX_LO(a6, (v).w, wt); FMX_HI(a7, (v).w, wt); } while (0)

#define ACC4(v, wt) do { \
        FMX_LO(a0, (v).x, wt); FMX_HI(a1, (v).x, wt); \
        FMX_LO(a2, (v).y, wt); FMX_HI(a3, (v).y, wt); } while (0)

// chunk<->block swizzle: consecutive chunks land on the same XCD (blockIdx%8 heuristic),
// so adjacent pairs-windows (shared 64B lines) merge in one L2 instead of ping-ponging.
__device__ __forceinline__ int chunk_of_block(int b) { return (b & 7) * (NCHUNK / 8) + (b >> 3); }

// ---- chunk histogram: block k histograms its 6250-edge slice in LDS (1024 thr) ----
__global__ __launch_bounds__(1024) void chunk_hist_kernel(const int* __restrict__ dst,
                                                          int* __restrict__ hist) {
    __shared__ int h[NBUCK];
    for (int i = threadIdx.x; i < NBUCK; i += 1024) h[i] = 0;
    __syncthreads();
    const int chunk = chunk_of_block(blockIdx.x);
    const int base = chunk * CHUNK_E;
    for (int j = threadIdx.x; j < CHUNK_E; j += 1024)
        atomicAdd(&h[dst[base + j] >> 8], 1);
    __syncthreads();
    for (int i = threadIdx.x; i < NBUCK; i += 1024)
        hist[i * NCHUNK + chunk] = h[i];
}

// ---- scan stage 1: per-256-block exclusive scan; block sums out.
//      Consumers add bsums[] themselves — no scan3 pass. ----
__global__ void scan1_kernel(int* __restrict__ data, int* __restrict__ bsums) {
    __shared__ int s[256];
    int i = blockIdx.x * 256 + threadIdx.x;
    int v = data[i];
    s[threadIdx.x] = v;
    __syncthreads();
    for (int off = 1; off < 256; off <<= 1) {
        int t = (threadIdx.x >= off) ? s[threadIdx.x - off] : 0;
        __syncthreads();
        s[threadIdx.x] += t;
        __syncthreads();
    }
    data[i] = s[threadIdx.x] - v;                   // exclusive within block
    if (threadIdx.x == 255) bsums[blockIdx.x] = s[255];
}

// ---- scan stage 2: exclusive scan of the 391 block sums (single block, 1 pass) ----
__global__ __launch_bounds__(1024) void scan2_kernel(int* __restrict__ bsums) {
    __shared__ int s[1024];
    int total = 0;
    for (int base = 0; base < SCAN_NB; base += 1024) {
        int i = base + threadIdx.x;
        int v = (i < SCAN_NB) ? bsums[i] : 0;
        s[threadIdx.x] = v;
        __syncthreads();
        for (int off = 1; off < 1024; off <<= 1) {
            int t = (threadIdx.x >= off) ? s[threadIdx.x - off] : 0;
            __syncthreads();
            s[threadIdx.x] += t;
            __syncthreads();
        }
        if (i < SCAN_NB) bsums[i] = total + s[threadIdx.x] - v;
        total += s[1023];
        __syncthreads();
    }
}

// ---- chunk fill: block k scatters its slice into PRIVATE windows.
//      Global offset of (bucket i, chunk) = hist[i*256+chunk] + bsums[i].
//      With 256-node buckets the mean window is 16 entries = one full 64-B line,
//      so the scatter touches ~4x fewer lines than the old 64-node buckets. ----
__global__ __launch_bounds__(1024) void chunk_fill_kernel(const int* __restrict__ src,
                                                          const int* __restrict__ dst,
                                                          const int* __restrict__ hist,
                                                          const int* __restrict__ bsums,
                                                          unsigned* __restrict__ pairs) {
    __shared__ int cur[NBUCK];
    const int chunk = chunk_of_block(blockIdx.x);
    for (int i = threadIdx.x; i < NBUCK; i += 1024)
        cur[i] = hist[i * NCHUNK + chunk] + bsums[i];
    __syncthreads();
    const int base = chunk * CHUNK_E;
    for (int j = threadIdx.x; j < CHUNK_E; j += 1024) {
        int d = dst[base + j];
        int pos = atomicAdd(&cur[d >> 8], 1);
        pairs[pos] = ((unsigned)src[base + j] << 8) | (unsigned)(d & 255);
    }
}

// ---- per-bucket counting sort -> node-level CSR, in place (LDS stage).
//      256 nodes/bucket, ~4096 edges staged in LDS (~40 KB incl. double buffer).
//      Sorted permutation staged in LDS (so[]) and written back COALESCED. ----
__global__ __launch_bounds__(256) void bucket_sort_kernel(const int* __restrict__ hist,
                                                          const int* __restrict__ bsums,
                                                          unsigned* __restrict__ pairs,
                                                          int* __restrict__ row_ptr,
                                                          float* __restrict__ dinv) {
    __shared__ unsigned sp[MAXB];
    __shared__ unsigned so[MAXB];
    __shared__ int hcnt[BNODES], scn[BNODES], cur[BNODES];
    const int b = blockIdx.x;
    const int beg = hist[b * NCHUNK] + bsums[b];
    const int end = (b + 1 < NBUCK) ? hist[(b + 1) * NCHUNK] + bsums[b + 1] : E_EDGES;
    const int cnt = end - beg;
    hcnt[threadIdx.x] = 0;
    __syncthreads();
    for (int j = threadIdx.x; j < cnt; j += 256) {
        unsigned p = pairs[beg + j];
        sp[j] = p;
        atomicAdd(&hcnt[p & 255], 1);
    }
    __syncthreads();
    scn[threadIdx.x] = hcnt[threadIdx.x];
    __syncthreads();
    for (int off = 1; off < BNODES; off <<= 1) {
        int t = (threadIdx.x >= off) ? scn[threadIdx.x - off] : 0;
        __syncthreads();
        scn[threadIdx.x] += t;
        __syncthreads();
    }
    {
        int ex = scn[threadIdx.x] - hcnt[threadIdx.x];   // exclusive
        cur[threadIdx.x] = ex;
        int node = b * BNODES + threadIdx.x;
        if (node < N_NODES) {
            row_ptr[node] = beg + ex;
            dinv[node] = rsqrtf((float)hcnt[threadIdx.x] + 1.0f);
        }
    }
    if (threadIdx.x == 0 && b == NBUCK - 1) row_ptr[N_NODES] = E_EDGES;
    __syncthreads();
    for (int j = threadIdx.x; j < cnt; j += 256) {
        unsigned p = sp[j];
        int pos = atomicAdd(&cur[p & 255], 1);
        so[pos] = p >> 8;                               // scatter stays in LDS
    }
    __syncthreads();
    for (int j = threadIdx.x; j < cnt; j += 256)
        pairs[beg + j] = so[j];                         // coalesced writeback
}

// ---- hs(fp16) = dinv[row] * (x @ W1) : 4 rows x 8 cols per thread, 128 rows/block ----
__global__ __launch_bounds__(256) void gemm1_kernel(const float* __restrict__ x,
                                                    const float* __restrict__ W1,
                                                    const float* __restrict__ dinv,
                                                    __half* __restrict__ hs) {
    __shared__ float sW[IN_C * HID_C];
    for (int i = threadIdx.x; i < IN_C * HID_C; i += 256) sW[i] = W1[i];
    __syncthreads();
    const int cg = (threadIdx.x & 7) * 8;
    const int row0 = blockIdx.x * 128 + (threadIdx.x >> 3) * 4;
    float acc[4][8];
#pragma unroll
    for (int r = 0; r < 4; ++r)
#pragma unroll
        for (int c = 0; c < 8; ++c) acc[r][c] = 0.f;

    int rr[4];
#pragma unroll
    for (int r = 0; r < 4; ++r) rr[r] = min(row0 + r, N_NODES - 1);

    const float4* x4 = (const float4*)x;
#pragma unroll 2
    for (int k4 = 0; k4 < IN_C / 4; ++k4) {
        float4 xv[4];
#pragma unroll
        for (int r = 0; r < 4; ++r) xv[r] = x4[(size_t)rr[r] * (IN_C / 4) + k4];
        float xs[4][4];
#pragma unroll
        for (int r = 0; r < 4; ++r) {
            xs[r][0] = xv[r].x; xs[r][1] = xv[r].y; xs[r][2] = xv[r].z; xs[r][3] = xv[r].w;
        }
#pragma unroll
        for (int kk = 0; kk < 4; ++kk) {
            const float4* wp = (const float4*)(sW + (k4 * 4 + kk) * HID_C + cg);
            float4 w0 = wp[0], w1 = wp[1];
            float wv[8] = {w0.x, w0.y, w0.z, w0.w, w1.x, w1.y, w1.z, w1.w};
#pragma unroll
            for (int r = 0; r < 4; ++r)
#pragma unroll
                for (int c = 0; c < 8; ++c)
                    acc[r][c] = fmaf(xs[r][kk], wv[c], acc[r][c]);
        }
    }
#pragma unroll
    for (int r = 0; r < 4; ++r) {
        int row = row0 + r;
        if (row < N_NODES) {
            float dv = dinv[row];
            union { float4 f; __half2 h[4]; } u;
#pragma unroll
            for (int q = 0; q < 4; ++q)
                u.h[q] = __floats2half2_rn(acc[r][2 * q] * dv, acc[r][2 * q + 1] * dv);
            *(float4*)(hs + (size_t)row * HID_C + cg) = u.f;   // 16 B packed store
        }
    }
}

// ---- layer-1 aggregate FUSED with gemm2. 8 nodes/wave, 8 lanes/node, uint4 (16B =
//      8 fp16 channels) per lane. One gather instruction = 8 edges x 128B rows = 1KB.
//      (round-3 proven form; 16-deep variant was neutral-negative in round 4) ----
__global__ __launch_bounds__(256) void agg1_gemm2_kernel(const int* __restrict__ row_ptr,
                                                         const int* __restrict__ col,
                                                         const __half* __restrict__ hs,
                                                         const float* __restrict__ dinv,
                                                         const float* __restrict__ b1,
                                                         const float* __restrict__ W2,
                                                         __half* __restrict__ gs) {
    __shared__ float sW[HID_C * OUT_C];                 // 8 KB, [k][c] row-major
    __shared__ float sh[32 * 68];                       // 32 nodes x 64ch, stride 68 (bank-spread)
    for (int i = threadIdx.x; i < HID_C * OUT_C; i += 256) sW[i] = W2[i];
    const int ln = threadIdx.x >> 3;                    // node slot 0..31
    const int cl = threadIdx.x & 7;                     // lane in node: channels 8cl..8cl+7
    const int node = blockIdx.x * 32 + ln;              // grid 3125 exact
    const int beg = row_ptr[node], end = row_ptr[node + 1];
    const char* hsb = (const char*)hs;
    const int lo = cl * 16;                             // byte offset within 128-B row
    float one = 1.0f;
    float a0 = 0.f, a1 = 0.f, a2 = 0.f, a3 = 0.f, a4 = 0.f, a5 = 0.f, a6 = 0.f, a7 = 0.f;
    {
        uint4 sv = *(const uint4*)(hsb + node * 128 + lo);   // self loop
        ACC8(sv, one);
    }
    int j = beg;
    for (; j + 8 <= end; j += 8) {                      // 8 independent gathers in flight
        int i0 = col[j],     i1 = col[j + 1], i2 = col[j + 2], i3 = col[j + 3];
        int i4 = col[j + 4], i5 = col[j + 5], i6 = col[j + 6], i7 = col[j + 7];
        uint4 v0 = *(const uint4*)(hsb + i0 * 128 + lo);
        uint4 v1 = *(const uint4*)(hsb + i1 * 128 + lo);
        uint4 v2 = *(const uint4*)(hsb + i2 * 128 + lo);
        uint4 v3 = *(const uint4*)(hsb + i3 * 128 + lo);
        uint4 v4 = *(const uint4*)(hsb + i4 * 128 + lo);
        uint4 v5 = *(const uint4*)(hsb + i5 * 128 + lo);
        uint4 v6 = *(const uint4*)(hsb + i6 * 128 + lo);
        uint4 v7 = *(const uint4*)(hsb + i7 * 128 + lo);
        ACC8(v0, one); ACC8(v1, one); ACC8(v2, one); ACC8(v3, one);
        ACC8(v4, one); ACC8(v5, one); ACC8(v6, one); ACC8(v7, one);
    }
    if (j < end) {                                      // predicated tail, 8 deep
        const int e1 = end - 1;
#pragma unroll
        for (int k = 0; k < 8; ++k) {
            int jj = j + k;
            int s = col[min(jj, e1)];
            float wt = (jj < end) ? 1.0f : 0.0f;
            uint4 v = *(const uint4*)(hsb + s * 128 + lo);
            ACC8(v, wt);
        }
    }
    const float dv = dinv[node];
    const float4* b4 = (const float4*)b1;
    float4 bb0 = b4[2 * cl], bb1 = b4[2 * cl + 1];
    float4 h0, h1;
    h0.x = fmaxf(fmaf(dv, a0, bb0.x), 0.f);
    h0.y = fmaxf(fmaf(dv, a1, bb0.y), 0.f);
    h0.z = fmaxf(fmaf(dv, a2, bb0.z), 0.f);
    h0.w = fmaxf(fmaf(dv, a3, bb0.w), 0.f);
    h1.x = fmaxf(fmaf(dv, a4, bb1.x), 0.f);
    h1.y = fmaxf(fmaf(dv, a5, bb1.y), 0.f);
    h1.z = fmaxf(fmaf(dv, a6, bb1.z), 0.f);
    h1.w = fmaxf(fmaf(dv, a7, bb1.w), 0.f);
    *(float4*)&sh[ln * 68 + 8 * cl] = h0;               // h2 row, fp32 in LDS
    *(float4*)&sh[ln * 68 + 8 * cl + 4] = h1;
    __syncthreads();                                    // also covers sW load
    // gs[node][oc..oc+3] = dv * sum_k h2[k] * W2[k][oc..oc+3]
    float g0 = 0.f, g1 = 0.f, g2 = 0.f, g3 = 0.f;
    const int oc = 4 * cl;
#pragma unroll
    for (int k4 = 0; k4 < HID_C / 4; ++k4) {
        float4 hv = *(const float4*)&sh[ln * 68 + 4 * k4];   // bank 4(ln+k4)%32: conflict-free
#pragma unroll
        for (int q = 0; q < 4; ++q) {
            float hq = (q == 0) ? hv.x : (q == 1) ? hv.y : (q == 2) ? hv.z : hv.w;
            float4 wv = *(const float4*)&sW[(4 * k4 + q) * OUT_C + oc];
            g0 = fmaf(hq, wv.x, g0);
            g1 = fmaf(hq, wv.y, g1);
            g2 = fmaf(hq, wv.z, g2);
            g3 = fmaf(hq, wv.w, g3);
        }
    }
    union { uint2 u; __half2 h[2]; } go;
    go.h[0] = __floats2half2_rn(g0 * dv, g1 * dv);
    go.h[1] = __floats2half2_rn(g2 * dv, g3 * dv);
    *(uint2*)(gs + (size_t)node * OUT_C + oc) = go.u;   // 8 B x 8 lanes = 64 B/node
}

// ---- layer-2 aggregate: 8 nodes/wave, 8 lanes/node, uint2 (8B = 4 fp16 ch) per lane.
//      (round-3 proven form; 4-lane/16-node-per-wave variant regressed in round 4,
//      most plausibly from degree-divergence across 16 nodes per wave) ----
__global__ __launch_bounds__(256) void agg2_kernel(const int* __restrict__ row_ptr,
                                                   const int* __restrict__ col,
                                                   const __half* __restrict__ gsr,
                                                   const float* __restrict__ dinv,
                                                   const float* __restrict__ b2,
                                                   float* __restrict__ out) {
    const int ln = threadIdx.x >> 3;                    // node slot 0..31
    const int cl = threadIdx.x & 7;                     // channels 4cl..4cl+3
    const int node = blockIdx.x * 32 + ln;              // grid 3125 exact
    const int beg = row_ptr[node], end = row_ptr[node + 1];
    const char* gb = (const char*)gsr;
    const int lo = cl * 8;                              // byte offset within 64-B row
    float one = 1.0f;
    float a0 = 0.f, a1 = 0.f, a2 = 0.f, a3 = 0.f;
    {
        uint2 sv = *(const uint2*)(gb + node * 64 + lo);     // self loop
        ACC4(sv, one);
    }
    int j = beg;
    for (; j + 8 <= end; j += 8) {
        int i0 = col[j],     i1 = col[j + 1], i2 = col[j + 2], i3 = col[j + 3];
        int i4 = col[j + 4], i5 = col[j + 5], i6 = col[j + 6], i7 = col[j + 7];
        uint2 v0 = *(const uint2*)(gb + i0 * 64 + lo);
        uint2 v1 = *(const uint2*)(gb + i1 * 64 + lo);
        uint2 v2 = *(const uint2*)(gb + i2 * 64 + lo);
        uint2 v3 = *(const uint2*)(gb + i3 * 64 + lo);
        uint2 v4 = *(const uint2*)(gb + i4 * 64 + lo);
        uint2 v5 = *(const uint2*)(gb + i5 * 64 + lo);
        uint2 v6 = *(const uint2*)(gb + i6 * 64 + lo);
        uint2 v7 = *(const uint2*)(gb + i7 * 64 + lo);
        ACC4(v0, one); ACC4(v1, one); ACC4(v2, one); ACC4(v3, one);
        ACC4(v4, one); ACC4(v5, one); ACC4(v6, one); ACC4(v7, one);
    }
    if (j < end) {                                      // predicated tail, 8 deep
        const int e1 = end - 1;
#pragma unroll
        for (int k = 0; k < 8; ++k) {
            int jj = j + k;
            int s = col[min(jj, e1)];
            float wt = (jj < end) ? 1.0f : 0.0f;
            uint2 v = *(const uint2*)(gb + s * 64 + lo);
            ACC4(v, wt);
        }
    }
    const float dv = dinv[node];
    float4 bb = ((const float4*)b2)[cl];
    float4 o;
    o.x = fmaf(dv, a0, bb.x);
    o.y = fmaf(dv, a1, bb.y);
    o.z = fmaf(dv, a2, bb.z);
    o.w = fmaf(dv, a3, bb.w);
    *(float4*)(out + (size_t)node * OUT_C + 4 * cl) = o;   // 16 B x 8 lanes = 128 B/node
}

extern "C" void kernel_launch(void* const* d_in, const int* in_sizes, int n_in,
                              void* d_out, int out_size, void* d_ws, size_t ws_size,
                              hipStream_t stream) {
    const float* x  = (const float*)d_in[0];   // [N,128]
    const int*   ei = (const int*)d_in[1];     // [2,E]
    const float* W1 = (const float*)d_in[2];   // [128,64]
    const float* b1 = (const float*)d_in[3];   // [64]
    const float* W2 = (const float*)d_in[4];   // [64,32]
    const float* b2 = (const float*)d_in[5];   // [32]
    float* out = (float*)d_out;                // [N,32]

    const int* srcv = ei;
    const int* dstv = ei + E_EDGES;

    // workspace layout (~33 MB)
    float* dinv  = (float*)d_ws;                           // N floats
    __half* hs   = (__half*)(dinv + N_NODES);              // N*64 halves (layer-1 features)
    __half* gs   = hs + (size_t)N_NODES * HID_C;           // N*32 halves (fused agg1+gemm2 out;
                                                           //  must NOT alias hs — read concurrently)
    int* hist      = (int*)(gs + (size_t)N_NODES * HID_C); // NBUCK*NCHUNK (100k)
    int* bsums     = hist + SCAN_N;                        // SCAN_NB (391)
    int* row_ptr   = bsums + SCAN_NB;                      // N+1
    unsigned* pairs = (unsigned*)(row_ptr + N_NODES + 1);  // E (pairs -> sorted src = col)
    int* col = (int*)pairs;

    // CSR build: chunk-privatized counting sort (scan3 folded into consumers)
    chunk_hist_kernel<<<NCHUNK, 1024, 0, stream>>>(dstv, hist);
    scan1_kernel<<<SCAN_NB, 256, 0, stream>>>(hist, bsums);
    scan2_kernel<<<1, 1024, 0, stream>>>(bsums);
    chunk_fill_kernel<<<NCHUNK, 1024, 0, stream>>>(srcv, dstv, hist, bsums, pairs);
    bucket_sort_kernel<<<NBUCK, 256, 0, stream>>>(hist, bsums, pairs, row_ptr, dinv);

    // layer 1 (+ fused layer-2 GEMM)
    gemm1_kernel<<<(N_NODES + 127) / 128, 256, 0, stream>>>(x, W1, dinv, hs);
    agg1_gemm2_kernel<<<N_NODES / 32, 256, 0, stream>>>(row_ptr, col, hs, dinv, b1, W2, gs);

    // layer 2 aggregate
    agg2_kernel<<<N_NODES / 32, 256, 0, stream>>>(row_ptr, col, gs, dinv, b2, out);
}

// Round 7
// 202.414 us; speedup vs baseline: 1.0238x; 1.0063x over previous
//
#include <hip/hip_runtime.h>
#include <hip/hip_fp16.h>

#define N_NODES 100000
#define E_EDGES 1600000
#define IN_C 128
#define HID_C 64
#define OUT_C 32
#define BNODES 256                                  // nodes per bucket (dst>>8)
#define NBUCK ((N_NODES + BNODES - 1) / BNODES)     // 391
#define MAXB 4608                                   // bucket cap (mean 4092, sd~64 -> +8 sigma)
#define NCHUNK 256                                  // edge chunks (privatized sort)
#define CHUNK_E (E_EDGES / NCHUNK)                  // 6250
#define SCAN_N (NBUCK * NCHUNK)                     // 100096 counts
#define SCAN_NB (SCAN_N / 256)                      // 391 blocks (bsums[i] pairs with hist row i)
#define NT 8                                        // src tiles (12.8MB hs / 8 = 1.6MB/tile)
#define TILE_DIV 12500                              // src / 12500 -> tile 0..7

// v_fma_mix_f32: acc(f32) += cvt_f32(f16 half of u) * wt(f32). One VALU per channel-value
// (vs cvt+add = 2), fp32 accumulation preserved exactly.
#define FMX_LO(acc, u, wt) asm("v_fma_mix_f32 %0, %1, %2, %0 op_sel:[0,0,0] op_sel_hi:[1,0,0]" \
                               : "+v"(acc) : "v"(u), "v"(wt))
#define FMX_HI(acc, u, wt) asm("v_fma_mix_f32 %0, %1, %2, %0 op_sel:[1,0,0] op_sel_hi:[1,0,0]" \
                               : "+v"(acc) : "v"(u), "v"(wt))

// NOTE: macro param must NOT be named 'w'/'x'/'y'/'z' — it would substitute into the
// vector member access (v).w (round-2 compile failure).
#define ACC8(v, wt) do { \
        FMX_LO(a0, (v).x, wt); FMX_HI(a1, (v).x, wt); \
        FMX_LO(a2, (v).y, wt); FMX_HI(a3, (v).y, wt); \
        FMX_LO(a4, (v).z, wt); FMX_HI(a5, (v).z, wt); \
        FMX_LO(a6, (v).w, wt); FMX_HI(a7, (v).w, wt); } while (0)

#define ACC4(v, wt) do { \
        FMX_LO(a0, (v).x, wt); FMX_HI(a1, (v).x, wt); \
        FMX_LO(a2, (v).y, wt); FMX_HI(a3, (v).y, wt); } while (0)

// chunk<->block swizzle: consecutive chunks land on the same XCD (blockIdx%8 heuristic),
// so adjacent pairs-windows (shared 64B lines) merge in one L2 instead of ping-ponging.
__device__ __forceinline__ int chunk_of_block(int b) { return (b & 7) * (NCHUNK / 8) + (b >> 3); }

// ---- chunk histogram: block k histograms its 6250-edge slice in LDS (1024 thr) ----
__global__ __launch_bounds__(1024) void chunk_hist_kernel(const int* __restrict__ dst,
                                                          int* __restrict__ hist) {
    __shared__ int h[NBUCK];
    for (int i = threadIdx.x; i < NBUCK; i += 1024) h[i] = 0;
    __syncthreads();
    const int chunk = chunk_of_block(blockIdx.x);
    const int base = chunk * CHUNK_E;
    for (int j = threadIdx.x; j < CHUNK_E; j += 1024)
        atomicAdd(&h[dst[base + j] >> 8], 1);
    __syncthreads();
    for (int i = threadIdx.x; i < NBUCK; i += 1024)
        hist[i * NCHUNK + chunk] = h[i];
}

// ---- scan stage 1: per-256-block (= per-bucket-row) exclusive scan; row totals out.
//      BUCKET-ORDERED bases restored (round-6 arrival-order windows broke row_ptr
//      monotonicity at bucket boundaries -> every 256th node read a garbage range). ----
__global__ void scan1_kernel(int* __restrict__ data, int* __restrict__ bsums) {
    __shared__ int s[256];
    int i = blockIdx.x * 256 + threadIdx.x;
    int v = data[i];
    s[threadIdx.x] = v;
    __syncthreads();
    for (int off = 1; off < 256; off <<= 1) {
        int t = (threadIdx.x >= off) ? s[threadIdx.x - off] : 0;
        __syncthreads();
        s[threadIdx.x] += t;
        __syncthreads();
    }
    data[i] = s[threadIdx.x] - v;                   // exclusive within bucket row
    if (threadIdx.x == 255) bsums[blockIdx.x] = s[255];
}

// ---- scan stage 2: exclusive scan of the 391 block sums (single block, 1 pass) ----
__global__ __launch_bounds__(1024) void scan2_kernel(int* __restrict__ bsums) {
    __shared__ int s[1024];
    int i = threadIdx.x;
    int v = (i < SCAN_NB) ? bsums[i] : 0;
    s[i] = v;
    __syncthreads();
    for (int off = 1; off < 1024; off <<= 1) {
        int t = (i >= off) ? s[i - off] : 0;
        __syncthreads();
        s[i] += t;
        __syncthreads();
    }
    if (i < SCAN_NB) bsums[i] = s[i] - v;
}

// ---- chunk fill: block k scatters its slice into PRIVATE windows.
//      Global offset of (bucket i, chunk) = hist[i*256+chunk] + bsums[i]. ----
__global__ __launch_bounds__(1024) void chunk_fill_kernel(const int* __restrict__ src,
                                                          const int* __restrict__ dst,
                                                          const int* __restrict__ hist,
                                                          const int* __restrict__ bsums,
                                                          unsigned* __restrict__ pairs) {
    __shared__ int cur[NBUCK];
    const int chunk = chunk_of_block(blockIdx.x);
    for (int i = threadIdx.x; i < NBUCK; i += 1024)
        cur[i] = hist[i * NCHUNK + chunk] + bsums[i];
    __syncthreads();
    const int base = chunk * CHUNK_E;
    for (int j = threadIdx.x; j < CHUNK_E; j += 1024) {
        int d = dst[base + j];
        int pos = atomicAdd(&cur[d >> 8], 1);
        pairs[pos] = ((unsigned)src[base + j] << 8) | (unsigned)(d & 255);
    }
}

// ---- per-bucket counting sort -> node-level CSR, in place (LDS stage).
//      Sort key = (node, src/12500): every node's neighbor list comes out ordered
//      by src-TILE (8 tiles x 1.6MB of hs). Concurrent aggregate waves then walk
//      src tiles roughly in phase, shrinking the instantaneous gather working set
//      from 12.8MB to ~2 tiles (~3.2MB) -> fits a 4MB XCD L2.
//      (fp32 summation-order change only; ~2^-20 noise vs 2^-9 absmax.) ----
__global__ __launch_bounds__(256) void bucket_sort_kernel(const int* __restrict__ bsums,
                                                          unsigned* __restrict__ pairs,
                                                          int* __restrict__ row_ptr,
                                                          float* __restrict__ dinv) {
    __shared__ unsigned sp[MAXB];
    __shared__ unsigned so[MAXB];
    __shared__ int cur[BNODES * NT];                // 2048 counters (node x tile)
    __shared__ int s256[BNODES];
    const int b = blockIdx.x;
    const int tid = threadIdx.x;
    const int beg = bsums[b];
    const int end = (b + 1 < NBUCK) ? bsums[b + 1] : E_EDGES;
    const int cnt = end - beg;
#pragma unroll
    for (int q = 0; q < NT; ++q) cur[tid * NT + q] = 0;
    __syncthreads();
    for (int j = tid; j < cnt; j += 256) {
        unsigned p = pairs[beg + j];
        sp[j] = p;
        atomicAdd(&cur[(p & 255) * NT + (p >> 8) / TILE_DIV], 1);
    }
    __syncthreads();
    int a[NT];
    int lsum = 0;
#pragma unroll
    for (int q = 0; q < NT; ++q) { a[q] = cur[tid * NT + q]; lsum += a[q]; }
    s256[tid] = lsum;
    __syncthreads();
    for (int off = 1; off < 256; off <<= 1) {       // inclusive scan over node totals
        int t = (tid >= off) ? s256[tid - off] : 0;
        __syncthreads();
        s256[tid] += t;
        __syncthreads();
    }
    int run = s256[tid] - lsum;                     // exclusive prefix for this node
    int node = b * BNODES + tid;
    if (node < N_NODES) {
        row_ptr[node] = beg + run;
        dinv[node] = rsqrtf((float)lsum + 1.0f);
    }
    if (tid == 0 && b == NBUCK - 1) row_ptr[N_NODES] = E_EDGES;
#pragma unroll
    for (int q = 0; q < NT; ++q) { cur[tid * NT + q] = run; run += a[q]; }
    __syncthreads();
    for (int j = tid; j < cnt; j += 256) {
        unsigned p = sp[j];
        int pos = atomicAdd(&cur[(p & 255) * NT + (p >> 8) / TILE_DIV], 1);
        so[pos] = p >> 8;                           // scatter stays in LDS
    }
    __syncthreads();
    for (int j = tid; j < cnt; j += 256)
        pairs[beg + j] = so[j];                     // coalesced writeback
}

// ---- hs(fp16) = dinv[row] * (x @ W1) : 4 rows x 8 cols per thread, 128 rows/block ----
__global__ __launch_bounds__(256) void gemm1_kernel(const float* __restrict__ x,
                                                    const float* __restrict__ W1,
                                                    const float* __restrict__ dinv,
                                                    __half* __restrict__ hs) {
    __shared__ float sW[IN_C * HID_C];
    for (int i = threadIdx.x; i < IN_C * HID_C; i += 256) sW[i] = W1[i];
    __syncthreads();
    const int cg = (threadIdx.x & 7) * 8;
    const int row0 = blockIdx.x * 128 + (threadIdx.x >> 3) * 4;
    float acc[4][8];
#pragma unroll
    for (int r = 0; r < 4; ++r)
#pragma unroll
        for (int c = 0; c < 8; ++c) acc[r][c] = 0.f;

    int rr[4];
#pragma unroll
    for (int r = 0; r < 4; ++r) rr[r] = min(row0 + r, N_NODES - 1);

    const float4* x4 = (const float4*)x;
#pragma unroll 2
    for (int k4 = 0; k4 < IN_C / 4; ++k4) {
        float4 xv[4];
#pragma unroll
        for (int r = 0; r < 4; ++r) xv[r] = x4[(size_t)rr[r] * (IN_C / 4) + k4];
        float xs[4][4];
#pragma unroll
        for (int r = 0; r < 4; ++r) {
            xs[r][0] = xv[r].x; xs[r][1] = xv[r].y; xs[r][2] = xv[r].z; xs[r][3] = xv[r].w;
        }
#pragma unroll
        for (int kk = 0; kk < 4; ++kk) {
            const float4* wp = (const float4*)(sW + (k4 * 4 + kk) * HID_C + cg);
            float4 w0 = wp[0], w1 = wp[1];
            float wv[8] = {w0.x, w0.y, w0.z, w0.w, w1.x, w1.y, w1.z, w1.w};
#pragma unroll
            for (int r = 0; r < 4; ++r)
#pragma unroll
                for (int c = 0; c < 8; ++c)
                    acc[r][c] = fmaf(xs[r][kk], wv[c], acc[r][c]);
        }
    }
#pragma unroll
    for (int r = 0; r < 4; ++r) {
        int row = row0 + r;
        if (row < N_NODES) {
            float dv = dinv[row];
            union { float4 f; __half2 h[4]; } u;
#pragma unroll
            for (int q = 0; q < 4; ++q)
                u.h[q] = __floats2half2_rn(acc[r][2 * q] * dv, acc[r][2 * q + 1] * dv);
            *(float4*)(hs + (size_t)row * HID_C + cg) = u.f;   // 16 B packed store
        }
    }
}

// ---- layer-1 aggregate FUSED with gemm2. 8 nodes/wave, 8 lanes/node, uint4 (16B =
//      8 fp16 channels) per lane. One gather instruction = 8 edges x 128B rows = 1KB.
//      Neighbor lists arrive src-tile-ordered (see bucket_sort) for L2 locality. ----
__global__ __launch_bounds__(256) void agg1_gemm2_kernel(const int* __restrict__ row_ptr,
                                                         const int* __restrict__ col,
                                                         const __half* __restrict__ hs,
                                                         const float* __restrict__ dinv,
                                                         const float* __restrict__ b1,
                                                         const float* __restrict__ W2,
                                                         __half* __restrict__ gs) {
    __shared__ float sW[HID_C * OUT_C];                 // 8 KB, [k][c] row-major
    __shared__ float sh[32 * 68];                       // 32 nodes x 64ch, stride 68 (bank-spread)
    for (int i = threadIdx.x; i < HID_C * OUT_C; i += 256) sW[i] = W2[i];
    const int ln = threadIdx.x >> 3;                    // node slot 0..31
    const int cl = threadIdx.x & 7;                     // lane in node: channels 8cl..8cl+7
    const int node = blockIdx.x * 32 + ln;              // grid 3125 exact
    const int beg = row_ptr[node], end = row_ptr[node + 1];
    const char* hsb = (const char*)hs;
    const int lo = cl * 16;                             // byte offset within 128-B row
    float one = 1.0f;
    float a0 = 0.f, a1 = 0.f, a2 = 0.f, a3 = 0.f, a4 = 0.f, a5 = 0.f, a6 = 0.f, a7 = 0.f;
    {
        uint4 sv = *(const uint4*)(hsb + node * 128 + lo);   // self loop
        ACC8(sv, one);
    }
    int j = beg;
    for (; j + 8 <= end; j += 8) {                      // 8 independent gathers in flight
        int i0 = col[j],     i1 = col[j + 1], i2 = col[j + 2], i3 = col[j + 3];
        int i4 = col[j + 4], i5 = col[j + 5], i6 = col[j + 6], i7 = col[j + 7];
        uint4 v0 = *(const uint4*)(hsb + i0 * 128 + lo);
        uint4 v1 = *(const uint4*)(hsb + i1 * 128 + lo);
        uint4 v2 = *(const uint4*)(hsb + i2 * 128 + lo);
        uint4 v3 = *(const uint4*)(hsb + i3 * 128 + lo);
        uint4 v4 = *(const uint4*)(hsb + i4 * 128 + lo);
        uint4 v5 = *(const uint4*)(hsb + i5 * 128 + lo);
        uint4 v6 = *(const uint4*)(hsb + i6 * 128 + lo);
        uint4 v7 = *(const uint4*)(hsb + i7 * 128 + lo);
        ACC8(v0, one); ACC8(v1, one); ACC8(v2, one); ACC8(v3, one);
        ACC8(v4, one); ACC8(v5, one); ACC8(v6, one); ACC8(v7, one);
    }
    if (j < end) {                                      // predicated tail, 8 deep
        const int e1 = end - 1;
#pragma unroll
        for (int k = 0; k < 8; ++k) {
            int jj = j + k;
            int s = col[min(jj, e1)];
            float wt = (jj < end) ? 1.0f : 0.0f;
            uint4 v = *(const uint4*)(hsb + s * 128 + lo);
            ACC8(v, wt);
        }
    }
    const float dv = dinv[node];
    const float4* b4 = (const float4*)b1;
    float4 bb0 = b4[2 * cl], bb1 = b4[2 * cl + 1];
    float4 h0, h1;
    h0.x = fmaxf(fmaf(dv, a0, bb0.x), 0.f);
    h0.y = fmaxf(fmaf(dv, a1, bb0.y), 0.f);
    h0.z = fmaxf(fmaf(dv, a2, bb0.z), 0.f);
    h0.w = fmaxf(fmaf(dv, a3, bb0.w), 0.f);
    h1.x = fmaxf(fmaf(dv, a4, bb1.x), 0.f);
    h1.y = fmaxf(fmaf(dv, a5, bb1.y), 0.f);
    h1.z = fmaxf(fmaf(dv, a6, bb1.z), 0.f);
    h1.w = fmaxf(fmaf(dv, a7, bb1.w), 0.f);
    *(float4*)&sh[ln * 68 + 8 * cl] = h0;               // h2 row, fp32 in LDS
    *(float4*)&sh[ln * 68 + 8 * cl + 4] = h1;
    __syncthreads();                                    // also covers sW load
    // gs[node][oc..oc+3] = dv * sum_k h2[k] * W2[k][oc..oc+3]
    float g0 = 0.f, g1 = 0.f, g2 = 0.f, g3 = 0.f;
    const int oc = 4 * cl;
#pragma unroll
    for (int k4 = 0; k4 < HID_C / 4; ++k4) {
        float4 hv = *(const float4*)&sh[ln * 68 + 4 * k4];   // bank 4(ln+k4)%32: conflict-free
#pragma unroll
        for (int q = 0; q < 4; ++q) {
            float hq = (q == 0) ? hv.x : (q == 1) ? hv.y : (q == 2) ? hv.z : hv.w;
            float4 wv = *(const float4*)&sW[(4 * k4 + q) * OUT_C + oc];
            g0 = fmaf(hq, wv.x, g0);
            g1 = fmaf(hq, wv.y, g1);
            g2 = fmaf(hq, wv.z, g2);
            g3 = fmaf(hq, wv.w, g3);
        }
    }
    union { uint2 u; __half2 h[2]; } go;
    go.h[0] = __floats2half2_rn(g0 * dv, g1 * dv);
    go.h[1] = __floats2half2_rn(g2 * dv, g3 * dv);
    *(uint2*)(gs + (size_t)node * OUT_C + oc) = go.u;   // 8 B x 8 lanes = 64 B/node
}

// ---- layer-2 aggregate: 8 nodes/wave, 8 lanes/node, uint2 (8B = 4 fp16 ch) per lane.
//      Benefits from the same src-tile-ordered col lists (gs tiles = 0.8 MB). ----
__global__ __launch_bounds__(256) void agg2_kernel(const int* __restrict__ row_ptr,
                                                   const int* __restrict__ col,
                                                   const __half* __restrict__ gsr,
                                                   const float* __restrict__ dinv,
                                                   const float* __restrict__ b2,
                                                   float* __restrict__ out) {
    const int ln = threadIdx.x >> 3;                    // node slot 0..31
    const int cl = threadIdx.x & 7;                     // channels 4cl..4cl+3
    const int node = blockIdx.x * 32 + ln;              // grid 3125 exact
    const int beg = row_ptr[node], end = row_ptr[node + 1];
    const char* gb = (const char*)gsr;
    const int lo = cl * 8;                              // byte offset within 64-B row
    float one = 1.0f;
    float a0 = 0.f, a1 = 0.f, a2 = 0.f, a3 = 0.f;
    {
        uint2 sv = *(const uint2*)(gb + node * 64 + lo);     // self loop
        ACC4(sv, one);
    }
    int j = beg;
    for (; j + 8 <= end; j += 8) {
        int i0 = col[j],     i1 = col[j + 1], i2 = col[j + 2], i3 = col[j + 3];
        int i4 = col[j + 4], i5 = col[j + 5], i6 = col[j + 6], i7 = col[j + 7];
        uint2 v0 = *(const uint2*)(gb + i0 * 64 + lo);
        uint2 v1 = *(const uint2*)(gb + i1 * 64 + lo);
        uint2 v2 = *(const uint2*)(gb + i2 * 64 + lo);
        uint2 v3 = *(const uint2*)(gb + i3 * 64 + lo);
        uint2 v4 = *(const uint2*)(gb + i4 * 64 + lo);
        uint2 v5 = *(const uint2*)(gb + i5 * 64 + lo);
        uint2 v6 = *(const uint2*)(gb + i6 * 64 + lo);
        uint2 v7 = *(const uint2*)(gb + i7 * 64 + lo);
        ACC4(v0, one); ACC4(v1, one); ACC4(v2, one); ACC4(v3, one);
        ACC4(v4, one); ACC4(v5, one); ACC4(v6, one); ACC4(v7, one);
    }
    if (j < end) {                                      // predicated tail, 8 deep
        const int e1 = end - 1;
#pragma unroll
        for (int k = 0; k < 8; ++k) {
            int jj = j + k;
            int s = col[min(jj, e1)];
            float wt = (jj < end) ? 1.0f : 0.0f;
            uint2 v = *(const uint2*)(gb + s * 64 + lo);
            ACC4(v, wt);
        }
    }
    const float dv = dinv[node];
    float4 bb = ((const float4*)b2)[cl];
    float4 o;
    o.x = fmaf(dv, a0, bb.x);
    o.y = fmaf(dv, a1, bb.y);
    o.z = fmaf(dv, a2, bb.z);
    o.w = fmaf(dv, a3, bb.w);
    *(float4*)(out + (size_t)node * OUT_C + 4 * cl) = o;   // 16 B x 8 lanes = 128 B/node
}

extern "C" void kernel_launch(void* const* d_in, const int* in_sizes, int n_in,
                              void* d_out, int out_size, void* d_ws, size_t ws_size,
                              hipStream_t stream) {
    const float* x  = (const float*)d_in[0];   // [N,128]
    const int*   ei = (const int*)d_in[1];     // [2,E]
    const float* W1 = (const float*)d_in[2];   // [128,64]
    const float* b1 = (const float*)d_in[3];   // [64]
    const float* W2 = (const float*)d_in[4];   // [64,32]
    const float* b2 = (const float*)d_in[5];   // [32]
    float* out = (float*)d_out;                // [N,32]

    const int* srcv = ei;
    const int* dstv = ei + E_EDGES;

    // workspace layout (~33 MB)
    float* dinv  = (float*)d_ws;                           // N floats
    __half* hs   = (__half*)(dinv + N_NODES);              // N*64 halves (layer-1 features)
    __half* gs   = hs + (size_t)N_NODES * HID_C;           // N*32 halves (fused agg1+gemm2 out;
                                                           //  must NOT alias hs — read concurrently)
    int* hist      = (int*)(gs + (size_t)N_NODES * HID_C); // NBUCK*NCHUNK (100k)
    int* bsums     = hist + SCAN_N;                        // NBUCK bucket base offsets
    int* row_ptr   = bsums + SCAN_NB;                      // N+1
    unsigned* pairs = (unsigned*)(row_ptr + N_NODES + 1);  // E (pairs -> sorted src = col)
    int* col = (int*)pairs;

    // CSR build: chunk-privatized counting sort (bucket-ordered scan, 5 kernels)
    chunk_hist_kernel<<<NCHUNK, 1024, 0, stream>>>(dstv, hist);
    scan1_kernel<<<SCAN_NB, 256, 0, stream>>>(hist, bsums);
    scan2_kernel<<<1, 1024, 0, stream>>>(bsums);
    chunk_fill_kernel<<<NCHUNK, 1024, 0, stream>>>(srcv, dstv, hist, bsums, pairs);
    bucket_sort_kernel<<<NBUCK, 256, 0, stream>>>(bsums, pairs, row_ptr, dinv);

    // layer 1 (+ fused layer-2 GEMM)
    gemm1_kernel<<<(N_NODES + 127) / 128, 256, 0, stream>>>(x, W1, dinv, hs);
    agg1_gemm2_kernel<<<N_NODES / 32, 256, 0, stream>>>(row_ptr, col, hs, dinv, b1, W2, gs);

    // layer 2 aggregate
    agg2_kernel<<<N_NODES / 32, 256, 0, stream>>>(row_ptr, col, gs, dinv, b2, out);
}